// Round 1
// baseline (206.781 us; speedup 1.0000x reference)
//
#include <hip/hip_runtime.h>
#include <hip/hip_bf16.h>

#define N_NODES  12288
#define N_FEAT   256
#define KDIM     128
#define N_GRAPHS 192

#define RPB 8           // rows per block in qk_proj
#define SJ  129         // padded K-row stride in LDS (floats): odd -> conflict-free
#define NMAX_FAST 120   // max graph size for the LDS fast path (mean 64, sigma 8)

// ---------------------------------------------------------------------------
// Kernel 1: segment starts via binary search (batch is sorted).
// starts[g] = first index i with batch[i] >= g, g in [0, 192]; starts[192]=N.
// ---------------------------------------------------------------------------
__global__ __launch_bounds__(256) void seg_starts_k(const int* __restrict__ batch,
                                                    int* __restrict__ starts) {
  int g = threadIdx.x;
  if (g > N_GRAPHS) return;
  int lo = 0, hi = N_NODES;
  while (lo < hi) {
    int mid = (lo + hi) >> 1;
    if (batch[mid] < g) lo = mid + 1; else hi = mid;
  }
  starts[g] = lo;
}

// ---------------------------------------------------------------------------
// Kernel 2: fused Q|K projection.  QK = X @ [Wq | Wk].
// Block = 256 threads (thread c -> output column; c<128 -> Q, else K),
// 8 rows per block. X elements are wave-uniform -> s_load broadcast, so the
// inner loop is 1 global W load + 8 scalar-operand FMAs per k.
// Score scale 1/sqrt(256) = 1/16 is folded into Q.
// ---------------------------------------------------------------------------
__global__ __launch_bounds__(256) void qk_proj_k(const float* __restrict__ X,
                                                 const float* __restrict__ Wq,
                                                 const float* __restrict__ Wk,
                                                 float* __restrict__ Qg,
                                                 float* __restrict__ Kg) {
  const int c  = threadIdx.x;
  const int r0 = blockIdx.x * RPB;
  const float* W = (c < KDIM) ? Wq : Wk;
  const int cc = c & (KDIM - 1);

  float acc[RPB];
#pragma unroll
  for (int r = 0; r < RPB; r++) acc[r] = 0.f;

#pragma unroll 4
  for (int k = 0; k < N_FEAT; k++) {
    float w = W[k * KDIM + cc];
#pragma unroll
    for (int r = 0; r < RPB; r++)
      acc[r] = fmaf(X[(r0 + r) * N_FEAT + k], w, acc[r]);
  }

  float* Og = (c < KDIM) ? Qg : Kg;
  const float scale = (c < KDIM) ? 0.0625f : 1.0f;  // 1/16 folded into Q
#pragma unroll
  for (int r = 0; r < RPB; r++)
    Og[(r0 + r) * KDIM + cc] = acc[r] * scale;
}

// ---------------------------------------------------------------------------
// Kernel 3: per-graph attention pooling. One block (256 thr) per graph.
//   w_j = sum_i softmax_row_i(QK^T)_j   (column-sum of attention)
//   u   = sum_j w_j * X_j               (never materialize V!)
//   out[g] = u @ Wv
// Fast path (n <= 120): K tile in LDS (stride 129 -> conflict-free reads and
// writes), 16 rows per pass (2 column-groups x 8 rows), Q via readfirstlane
// scalar broadcast, shuffle-reduced softmax.
// Slow path (n > 120, practically never): global two-pass softmax.
// ---------------------------------------------------------------------------
__global__ __launch_bounds__(256) void attn_pool_k(const float* __restrict__ X,
                                                   const int* __restrict__ starts,
                                                   const float* __restrict__ Qg,
                                                   const float* __restrict__ Kg,
                                                   const float* __restrict__ Wv,
                                                   float* __restrict__ out,
                                                   float* __restrict__ wbuf,
                                                   float* __restrict__ wtmp) {
  __shared__ float Ks[NMAX_FAST * SJ];   // 61,920 B
  __shared__ float w2[256];              // per-group column weights
  __shared__ float redm[4][8];
  __shared__ float redl[4][8];
  __shared__ float u_lds[256];
  __shared__ float red1[4];

  const int g    = blockIdx.x;
  const int tid  = threadIdx.x;
  const int lane = tid & 63;
  const int wid  = tid >> 6;
  const int grp  = tid >> 7;    // 0: waves 0-1, 1: waves 2-3
  const int j    = tid & 127;   // column index within graph

  const int i0 = starts[g];
  const int n  = starts[g + 1] - i0;
  const float NEG_INF = -__builtin_inff();

  const bool fast = (n <= NMAX_FAST);

  if (fast) {
    // ---- stage K tile into LDS (padded row-major) ----
    for (int idx = tid; idx < n * KDIM; idx += 256) {
      int jj = idx >> 7, kk = idx & (KDIM - 1);
      Ks[jj * SJ + kk] = Kg[(i0 + jj) * KDIM + kk];
    }
    __syncthreads();

    float wacc = 0.f;  // this thread's accumulated column weight for column j
    for (int ibase = 0; ibase < n; ibase += 16) {
      const int rowb = ibase + grp * 8;

      // Q row pointers (wave-uniform -> scalar loads)
      const float* qrow[8];
#pragma unroll
      for (int r = 0; r < 8; r++) {
        int row = rowb + r;
        if (row >= n) row = 0;                       // clamp for safe address
        row = __builtin_amdgcn_readfirstlane(row);
        qrow[r] = Qg + (i0 + row) * KDIM;
      }

      // ---- scores: 8 rows x this thread's column ----
      float acc[8];
#pragma unroll
      for (int r = 0; r < 8; r++) acc[r] = 0.f;
      const float* kp = &Ks[j * SJ];
#pragma unroll 4
      for (int k = 0; k < KDIM; k++) {
        float kt = kp[k];
#pragma unroll
        for (int r = 0; r < 8; r++)
          acc[r] = fmaf(qrow[r][k], kt, acc[r]);
      }

      // mask invalid columns / rows
#pragma unroll
      for (int r = 0; r < 8; r++)
        if (j >= n || rowb + r >= n) acc[r] = NEG_INF;

      // ---- row max over the group's 128 lanes ----
#pragma unroll
      for (int r = 0; r < 8; r++) {
        float v = acc[r];
        for (int off = 32; off >= 1; off >>= 1)
          v = fmaxf(v, __shfl_xor(v, off, 64));
        if (lane == 0) redm[wid][r] = v;
      }
      __syncthreads();

      // ---- exp + row sum ----
      float e[8];
#pragma unroll
      for (int r = 0; r < 8; r++) {
        float m = fmaxf(redm[grp * 2][r], redm[grp * 2 + 1][r]);
        float v = __expf(acc[r] - m);   // NaN for fully-invalid rows: masked below
        e[r] = v;
        for (int off = 32; off >= 1; off >>= 1)
          v += __shfl_xor(v, off, 64);
        if (lane == 0) redl[wid][r] = v;
      }
      __syncthreads();

      // ---- accumulate column weights ----
#pragma unroll
      for (int r = 0; r < 8; r++) {
        float l = redl[grp * 2][r] + redl[grp * 2 + 1][r];
        float c = e[r] * (1.f / l);
        wacc += (rowb + r < n) ? c : 0.f;
      }
      // no barrier needed here: next pass's redm write is after its own sync
    }
    w2[tid] = wacc;
    __syncthreads();
  } else {
    // ---- generic slow path (correctness backstop, n > 120) ----
    for (int jj = tid; jj < n; jj += 256) wbuf[i0 + jj] = 0.f;
    __syncthreads();
    for (int i = 0; i < n; i++) {
      const float* qr = Qg + (i0 + i) * KDIM;
      float lmax = NEG_INF;
      for (int jj = tid; jj < n; jj += 256) {
        const float* kr = Kg + (i0 + jj) * KDIM;
        float s = 0.f;
        for (int k = 0; k < KDIM; k++) s = fmaf(qr[k], kr[k], s);
        wtmp[i0 + jj] = s;
        lmax = fmaxf(lmax, s);
      }
      float v = lmax;
      for (int off = 32; off >= 1; off >>= 1) v = fmaxf(v, __shfl_xor(v, off, 64));
      if (lane == 0) red1[wid] = v;
      __syncthreads();
      float m = fmaxf(fmaxf(red1[0], red1[1]), fmaxf(red1[2], red1[3]));
      __syncthreads();
      float lsum = 0.f;
      for (int jj = tid; jj < n; jj += 256) {
        float ev = __expf(wtmp[i0 + jj] - m);
        wtmp[i0 + jj] = ev;
        lsum += ev;
      }
      v = lsum;
      for (int off = 32; off >= 1; off >>= 1) v += __shfl_xor(v, off, 64);
      if (lane == 0) red1[wid] = v;
      __syncthreads();
      float invl = 1.f / (red1[0] + red1[1] + red1[2] + red1[3]);
      for (int jj = tid; jj < n; jj += 256)
        wbuf[i0 + jj] += wtmp[i0 + jj] * invl;
      __syncthreads();
    }
  }

  // ---- u[f] = sum_j w_j * X[i0+j][f]  (coalesced X reads) ----
  const int f = tid;
  float uacc = 0.f;
  if (fast) {
#pragma unroll 4
    for (int jj = 0; jj < n; jj++)
      uacc = fmaf(w2[jj] + w2[128 + jj], X[(i0 + jj) * N_FEAT + f], uacc);
  } else {
#pragma unroll 4
    for (int jj = 0; jj < n; jj++)
      uacc = fmaf(wbuf[i0 + jj], X[(i0 + jj) * N_FEAT + f], uacc);
  }
  u_lds[f] = uacc;
  __syncthreads();

  // ---- out[g] = u @ Wv ----
  float oacc = 0.f;
#pragma unroll 4
  for (int k = 0; k < N_FEAT; k++)
    oacc = fmaf(u_lds[k], Wv[k * N_FEAT + f], oacc);
  out[g * N_FEAT + f] = oacc;
}

// ---------------------------------------------------------------------------
extern "C" void kernel_launch(void* const* d_in, const int* in_sizes, int n_in,
                              void* d_out, int out_size, void* d_ws, size_t ws_size,
                              hipStream_t stream) {
  const float* X     = (const float*)d_in[0];
  const int*   batch = (const int*)d_in[1];
  const float* Wq    = (const float*)d_in[2];
  const float* Wk    = (const float*)d_in[3];
  const float* Wv    = (const float*)d_in[4];
  float* out = (float*)d_out;

  int*   starts = (int*)d_ws;
  float* Qg     = (float*)((char*)d_ws + 1024);
  float* Kg     = Qg + N_NODES * KDIM;
  float* wbuf   = Kg + N_NODES * KDIM;
  float* wtmp   = wbuf + N_NODES;
  // total ws use: 1 KB + 2*6.29 MB + 2*48 KB ~= 12.7 MB

  seg_starts_k<<<1, 256, 0, stream>>>(batch, starts);
  qk_proj_k<<<N_NODES / RPB, 256, 0, stream>>>(X, Wq, Wk, Qg, Kg);
  attn_pool_k<<<N_GRAPHS, 256, 0, stream>>>(X, starts, Qg, Kg, Wv, out, wbuf, wtmp);
}

// Round 2
// 144.921 us; speedup vs baseline: 1.4269x; 1.4269x over previous
//
#include <hip/hip_runtime.h>
#include <hip/hip_bf16.h>

#define N_NODES  12288
#define N_FEAT   256
#define KDIM     128
#define N_GRAPHS 192
#define NMAX     112     // LDS fast-path max graph size
#define NQ       4       // row-quarters per graph

// workspace layout (bytes)
#define WS_STARTS 0
#define WS_U      1024
#define WS_WSLOW  (WS_U + N_GRAPHS * N_FEAT * 4)      // 197632
#define WS_QG     (WS_WSLOW + N_NODES * 4)            // 246784 (16B aligned)
#define WS_KG     (WS_QG + N_NODES * KDIM * 4)

// ---------------------------------------------------------------------------
// Kernel 1: segment starts via binary search (batch is sorted).
// ---------------------------------------------------------------------------
__global__ __launch_bounds__(256) void seg_starts_k(const int* __restrict__ batch,
                                                    int* __restrict__ starts) {
  int g = threadIdx.x;
  if (g > N_GRAPHS) return;
  int lo = 0, hi = N_NODES;
  while (lo < hi) {
    int mid = (lo + hi) >> 1;
    if (batch[mid] < g) lo = mid + 1; else hi = mid;
  }
  starts[g] = lo;
}

// ---------------------------------------------------------------------------
// Kernel 2: fused Q|K projection, LDS-staged X (vector path only, no s_load
// of bulk data). Block: 256 thr = 64 col-pairs x 4 row-groups; 32-row slab.
// Thread computes 8 rows x {Q[2cc],Q[2cc+1],K[2cc],K[2cc+1]}.
// Scale 1/16 folded into Q.
// ---------------------------------------------------------------------------
__global__ __launch_bounds__(256) void qk_proj_k(const float* __restrict__ X,
                                                 const float* __restrict__ Wq,
                                                 const float* __restrict__ Wk,
                                                 float* __restrict__ Qg,
                                                 float* __restrict__ Kg) {
  __shared__ float4 Xs4[32 * 64];   // 32 rows x 256 floats = 32 KB
  const int tid = threadIdx.x;
  const int cc  = tid & 63;         // column pair
  const int rg  = tid >> 6;         // row group (8 rows)
  const int r0  = blockIdx.x * 32;

  const float4* Xg4 = (const float4*)(X + (size_t)r0 * N_FEAT);
#pragma unroll
  for (int i = 0; i < 8; i++)
    Xs4[tid + i * 256] = Xg4[tid + i * 256];
  __syncthreads();

  float acc[8][4];
#pragma unroll
  for (int r = 0; r < 8; r++)
#pragma unroll
    for (int c = 0; c < 4; c++) acc[r][c] = 0.f;

  for (int kq = 0; kq < 64; kq++) {
    float2 wq[4], wk[4];
#pragma unroll
    for (int c = 0; c < 4; c++) {
      wq[c] = *(const float2*)&Wq[(4 * kq + c) * KDIM + 2 * cc];
      wk[c] = *(const float2*)&Wk[(4 * kq + c) * KDIM + 2 * cc];
    }
#pragma unroll
    for (int r = 0; r < 8; r++) {
      float4 x = Xs4[(rg * 8 + r) * 64 + kq];   // broadcast read
      acc[r][0] = fmaf(x.x, wq[0].x, acc[r][0]);
      acc[r][1] = fmaf(x.x, wq[0].y, acc[r][1]);
      acc[r][2] = fmaf(x.x, wk[0].x, acc[r][2]);
      acc[r][3] = fmaf(x.x, wk[0].y, acc[r][3]);
      acc[r][0] = fmaf(x.y, wq[1].x, acc[r][0]);
      acc[r][1] = fmaf(x.y, wq[1].y, acc[r][1]);
      acc[r][2] = fmaf(x.y, wk[1].x, acc[r][2]);
      acc[r][3] = fmaf(x.y, wk[1].y, acc[r][3]);
      acc[r][0] = fmaf(x.z, wq[2].x, acc[r][0]);
      acc[r][1] = fmaf(x.z, wq[2].y, acc[r][1]);
      acc[r][2] = fmaf(x.z, wk[2].x, acc[r][2]);
      acc[r][3] = fmaf(x.z, wk[2].y, acc[r][3]);
      acc[r][0] = fmaf(x.w, wq[3].x, acc[r][0]);
      acc[r][1] = fmaf(x.w, wq[3].y, acc[r][1]);
      acc[r][2] = fmaf(x.w, wk[3].x, acc[r][2]);
      acc[r][3] = fmaf(x.w, wk[3].y, acc[r][3]);
    }
  }

#pragma unroll
  for (int r = 0; r < 8; r++) {
    int row = r0 + rg * 8 + r;
    *(float2*)&Qg[row * KDIM + 2 * cc] = make_float2(acc[r][0] * 0.0625f, acc[r][1] * 0.0625f);
    *(float2*)&Kg[row * KDIM + 2 * cc] = make_float2(acc[r][2], acc[r][3]);
  }
}

// ---------------------------------------------------------------------------
// Kernel 3: per-(graph, row-quarter) attention column weights + partial u.
// 512 threads. K in XOR-swizzled LDS (b128, conflict-free, aligned).
// Each wave owns distinct rows -> no cross-wave softmax traffic, one barrier.
// Q broadcast via v_readlane (VALU pipe). Slow path (n > NMAX): qi==0 block
// does everything via global memory + wslow atomics (correctness backstop).
// ---------------------------------------------------------------------------
__global__ __launch_bounds__(512) void attn_w_k(const float* __restrict__ X,
                                                const int* __restrict__ starts,
                                                const float* __restrict__ Qg,
                                                const float* __restrict__ Kg,
                                                float* __restrict__ U,
                                                float* __restrict__ wslow) {
  __shared__ float4 Ks4[NMAX * 32];   // 57344 B, swizzled: slot = j*32 + (kq ^ (j&31))
  __shared__ float w_lds[8][128];
  __shared__ float w2[128];

  const int tid  = threadIdx.x;
  const int lane = tid & 63;
  const int wv   = tid >> 6;
  const int g    = blockIdx.x >> 2;
  const int qi   = blockIdx.x & 3;

  const int i0 = starts[g];
  const int n  = starts[g + 1] - i0;
  const bool fast = (n <= NMAX);
  if (!fast && qi != 0) return;   // slow: one block handles the whole graph

  const int qlen = fast ? ((n + NQ - 1) >> 2) : n;
  const int q0 = i0 + qi * qlen;
  const int q1 = min(i0 + n, q0 + qlen);
  const float BIG = 1e30f;

  if (fast) {
    const float4* Kg4 = (const float4*)(Kg + (size_t)i0 * KDIM);
    for (int idx = tid; idx < n * 32; idx += 512) {
      int j = idx >> 5, kq = idx & 31;
      Ks4[j * 32 + (kq ^ (j & 31))] = Kg4[idx];
    }
  }
  __syncthreads();

  float wacc0 = 0.f, wacc1 = 0.f;

  if (fast) {
    const int j1 = lane;
    const int j2 = 64 + lane;
    const int j2c = (j2 < NMAX) ? j2 : 0;   // clamp LDS address (masked later)
    const int xo = lane & 31;
    for (int rb = q0 + 4 * wv; rb < q1; rb += 32) {
      float2 q[4];
#pragma unroll
      for (int r = 0; r < 4; r++) {
        int row = (rb + r < q1) ? (rb + r) : q0;
        q[r] = *(const float2*)&Qg[row * KDIM + 2 * lane];
      }
      float s0[4] = {0.f, 0.f, 0.f, 0.f};
      float s1[4] = {0.f, 0.f, 0.f, 0.f};
      for (int kq = 0; kq < 32; kq++) {
        float4 k0 = Ks4[j1 * 32 + (kq ^ xo)];
        float4 k1 = Ks4[j2c * 32 + (kq ^ xo)];
        const float k0a[4] = {k0.x, k0.y, k0.z, k0.w};
        const float k1a[4] = {k1.x, k1.y, k1.z, k1.w};
#pragma unroll
        for (int c = 0; c < 4; c++) {
          int sl = 2 * kq + (c >> 1);   // source lane for q element k=4kq+c
#pragma unroll
          for (int r = 0; r < 4; r++) {
            float qv = __uint_as_float(__builtin_amdgcn_readlane(
                __float_as_uint((c & 1) ? q[r].y : q[r].x), sl));
            s0[r] = fmaf(qv, k0a[c], s0[r]);
            s1[r] = fmaf(qv, k1a[c], s1[r]);
          }
        }
      }
#pragma unroll
      for (int r = 0; r < 4; r++) {
        if (j1 >= n) s0[r] = -BIG;
        if (j2 >= n) s1[r] = -BIG;
      }
#pragma unroll
      for (int r = 0; r < 4; r++) {
        float m = fmaxf(s0[r], s1[r]);
        for (int off = 32; off; off >>= 1) m = fmaxf(m, __shfl_xor(m, off));
        float e0 = __expf(s0[r] - m);
        float e1 = __expf(s1[r] - m);
        float l = e0 + e1;
        for (int off = 32; off; off >>= 1) l += __shfl_xor(l, off);
        float inv = 1.f / l;
        bool rv = (rb + r < q1);
        wacc0 += rv ? e0 * inv : 0.f;
        wacc1 += rv ? e1 * inv : 0.f;
      }
    }
  } else {
    // -------- slow path: whole graph, global K, two-pass online softmax ----
    for (int i = q0 + wv; i < q1; i += 8) {
      float2 q = *(const float2*)&Qg[i * KDIM + 2 * lane];
      float m_run = -BIG, l_run = 0.f;
      for (int jb = 0; jb < n; jb += 128) {
        float s0 = 0.f, s1 = 0.f;
        int ja = i0 + jb + lane, jbn = i0 + jb + 64 + lane;
        int jac = (jb + lane < n) ? ja : i0;
        int jbc = (jb + 64 + lane < n) ? jbn : i0;
        for (int k = 0; k < KDIM; k++) {
          float qv = __uint_as_float(__builtin_amdgcn_readlane(
              __float_as_uint((k & 1) ? q.y : q.x), k >> 1));
          s0 = fmaf(qv, Kg[jac * KDIM + k], s0);
          s1 = fmaf(qv, Kg[jbc * KDIM + k], s1);
        }
        if (jb + lane >= n) s0 = -BIG;
        if (jb + 64 + lane >= n) s1 = -BIG;
        float mc = fmaxf(s0, s1);
        for (int off = 32; off; off >>= 1) mc = fmaxf(mc, __shfl_xor(mc, off));
        float m_new = fmaxf(m_run, mc);
        float lc = __expf(s0 - m_new) + __expf(s1 - m_new);
        for (int off = 32; off; off >>= 1) lc += __shfl_xor(lc, off);
        l_run = l_run * __expf(m_run - m_new) + lc;
        m_run = m_new;
      }
      float inv = 1.f / l_run;
      for (int jb = 0; jb < n; jb += 128) {
        float s0 = 0.f, s1 = 0.f;
        int jac = (jb + lane < n) ? (i0 + jb + lane) : i0;
        int jbc = (jb + 64 + lane < n) ? (i0 + jb + 64 + lane) : i0;
        for (int k = 0; k < KDIM; k++) {
          float qv = __uint_as_float(__builtin_amdgcn_readlane(
              __float_as_uint((k & 1) ? q.y : q.x), k >> 1));
          s0 = fmaf(qv, Kg[jac * KDIM + k], s0);
          s1 = fmaf(qv, Kg[jbc * KDIM + k], s1);
        }
        if (jb + lane < n) atomicAdd(&wslow[i0 + jb + lane], __expf(s0 - m_run) * inv);
        if (jb + 64 + lane < n) atomicAdd(&wslow[i0 + jb + 64 + lane], __expf(s1 - m_run) * inv);
      }
    }
  }

  w_lds[wv][lane] = wacc0;
  w_lds[wv][64 + lane] = wacc1;
  __syncthreads();

  if (tid < 128) {
    float t = 0.f;
#pragma unroll
    for (int ww = 0; ww < 8; ww++) t += w_lds[ww][tid];
    w2[tid] = t;
  }
  __syncthreads();

  // ---- partial u[f] = sum_j w[j] * X[i0+j][f], atomic into U[g][f] ----
  const int f  = tid & 255;
  const int jp = tid >> 8;
  float ua = 0.f, ub = 0.f;
  if (fast) {
    int j = jp;
    for (; j + 2 < n; j += 4) {
      ua = fmaf(w2[j],     X[(size_t)(i0 + j) * N_FEAT + f], ua);
      ub = fmaf(w2[j + 2], X[(size_t)(i0 + j + 2) * N_FEAT + f], ub);
    }
    for (; j < n; j += 2)
      ua = fmaf(w2[j], X[(size_t)(i0 + j) * N_FEAT + f], ua);
  } else {
    for (int j = jp; j < n; j += 2) {
      float wj = atomicAdd(&wslow[i0 + j], 0.f);   // coherent read
      ua = fmaf(wj, X[(size_t)(i0 + j) * N_FEAT + f], ua);
    }
  }
  atomicAdd(&U[g * N_FEAT + f], ua + ub);
}

// ---------------------------------------------------------------------------
// Kernel 4: out[g] = U[g] @ Wv.  192 blocks x 512 thr (f x k-half).
// ---------------------------------------------------------------------------
__global__ __launch_bounds__(512) void vout_k(const float* __restrict__ U,
                                              const float* __restrict__ Wv,
                                              float* __restrict__ out) {
  __shared__ float Us[256];
  __shared__ float part[256];
  const int g   = blockIdx.x;
  const int tid = threadIdx.x;
  const int f   = tid & 255;
  const int kh  = tid >> 8;

  if (tid < 256) Us[tid] = U[g * N_FEAT + tid];
  __syncthreads();

  const float* wp = Wv + (size_t)kh * 128 * N_FEAT + f;
  const float* us = &Us[kh * 128];
  float a0 = 0.f, a1 = 0.f, a2 = 0.f, a3 = 0.f;
#pragma unroll
  for (int k = 0; k < 128; k += 4) {
    a0 = fmaf(us[k],     wp[(size_t)k * N_FEAT], a0);
    a1 = fmaf(us[k + 1], wp[(size_t)(k + 1) * N_FEAT], a1);
    a2 = fmaf(us[k + 2], wp[(size_t)(k + 2) * N_FEAT], a2);
    a3 = fmaf(us[k + 3], wp[(size_t)(k + 3) * N_FEAT], a3);
  }
  float acc = (a0 + a1) + (a2 + a3);
  if (kh == 1) part[f] = acc;
  __syncthreads();
  if (kh == 0) out[g * N_FEAT + f] = acc + part[f];
}

// ---------------------------------------------------------------------------
extern "C" void kernel_launch(void* const* d_in, const int* in_sizes, int n_in,
                              void* d_out, int out_size, void* d_ws, size_t ws_size,
                              hipStream_t stream) {
  const float* X     = (const float*)d_in[0];
  const int*   batch = (const int*)d_in[1];
  const float* Wq    = (const float*)d_in[2];
  const float* Wk    = (const float*)d_in[3];
  const float* Wv    = (const float*)d_in[4];
  float* out = (float*)d_out;

  char* ws = (char*)d_ws;
  int*   starts = (int*)(ws + WS_STARTS);
  float* U      = (float*)(ws + WS_U);
  float* wslow  = (float*)(ws + WS_WSLOW);
  float* Qg     = (float*)(ws + WS_QG);
  float* Kg     = (float*)(ws + WS_KG);

  hipMemsetAsync(ws + WS_U, 0, N_GRAPHS * N_FEAT * 4 + N_NODES * 4, stream);
  seg_starts_k<<<1, 256, 0, stream>>>(batch, starts);
  qk_proj_k<<<N_NODES / 32, 256, 0, stream>>>(X, Wq, Wk, Qg, Kg);
  attn_w_k<<<N_GRAPHS * NQ, 512, 0, stream>>>(X, starts, Qg, Kg, U, wslow);
  vout_k<<<N_GRAPHS, 512, 0, stream>>>(U, Wv, out);
}